// Round 2
// baseline (3262.695 us; speedup 1.0000x reference)
//
#include <hip/hip_runtime.h>
#include <hip/hip_bf16.h>
#include <math.h>

// ---------------------------------------------------------------------------
// EncoderLayer fp32 baseline for MI355X.
// B=8, S=2048, D_MODEL=512, H=8, DK=64, D_FF=2048, M = B*S = 16384.
// Pipeline:
//   1) q,k,v = x @ wq/wk/wv          (per-head GEMM, PERM_C output layout)
//   2) flash attention (in-place O over q)
//   3) y = concat(O) @ wo + x        (PERM_A input layout, fused residual)
//   4) x1 = LN(y; ln1)               (x1 lives in d_out)
//   5) hidden = relu(x1 @ w1 + b1)   (chunked over rows to fit ws_size)
//   6) y2 = hidden @ w2 + b2 + x1
//   7) out = LN(y2; ln2)
//
// Workspace budget: q,k,v = 3 x 33.55 MB; y/y2 alias the k buffer; x1 lives
// in d_out; the FFN hidden buffer is sized from the REMAINING ws_size
// (chunked row-wise if needed). Minimum ws ~101.2 MB.
// ---------------------------------------------------------------------------

#define D_MODEL 512
#define NHEAD   8
#define DK      64
#define SEQ     2048
#define BATCH   8
#define DFF     2048
#define MROWS   (BATCH * SEQ)          // 16384

// ---------------------------------------------------------------------------
// Generic tiled GEMM: C[M,N] = A[M,K] * B[K,N]  (+bias, +relu, +residual)
// 64x64 tile, BK=16, 256 threads, 4x4 spread micro-tile.
// PERM_A: A is the attention-output tensor O[b,h,s,dk] read as [M, H*DK]
// PERM_C: per-head weight (Bw[h,d,dk]) and per-head output layout (q/k/v)
// ---------------------------------------------------------------------------
template<bool PERM_A, bool PERM_C, bool HAS_BIAS, bool DO_RELU, bool HAS_RES>
__global__ __launch_bounds__(256)
void gemm_kernel(const float* __restrict__ A, const float* __restrict__ Bw,
                 const float* __restrict__ bias, const float* __restrict__ res,
                 float* __restrict__ C,
                 int lda, int ldb, int ldc, int Kdim)
{
    __shared__ float As[64][20];   // [row][k]  stride 20: float4-aligned
    __shared__ float Bst[64][20];  // [col][k]  transposed: inner reads b64 along k

    const int tid = threadIdx.x;
    const int tx = tid & 15;       // col group
    const int ty = tid >> 4;       // row group
    const int col0 = blockIdx.x * 64;
    const int row0 = blockIdx.y * 64;

    const float* Ab;
    if constexpr (PERM_A) {
        const int b = row0 >> 11;            // row0 / SEQ
        const int s0 = row0 & 2047;
        Ab = A + (size_t)b * (NHEAD * SEQ * DK) + (size_t)s0 * DK;
    } else {
        Ab = A + (size_t)row0 * lda;
    }
    const float* Bb;
    if constexpr (PERM_C) {
        // blockIdx.x == head; weight block is row-major [Kdim, 64]
        Bb = Bw + (size_t)blockIdx.x * Kdim * DK;
    } else {
        Bb = Bw + col0;
    }

    float acc[4][4];
    #pragma unroll
    for (int j = 0; j < 4; ++j)
        #pragma unroll
        for (int i = 0; i < 4; ++i) acc[j][i] = 0.f;

    const int ar = tid >> 2;            // A stage: row, 4 k-floats
    const int ak = (tid & 3) << 2;
    const int bk = tid >> 4;            // B stage: k-row, 4 n-floats
    const int bn = (tid & 15) << 2;

    for (int kt = 0; kt < Kdim; kt += 16) {
        const float* ap;
        if constexpr (PERM_A) {
            // k index selects head h = kt/64, offset kt%64 within the head's dk
            ap = Ab + (size_t)(kt >> 6) * (SEQ * DK) + (kt & 63) + ar * DK + ak;
        } else {
            ap = Ab + (size_t)ar * lda + kt + ak;
        }
        const float4 av = *(const float4*)ap;
        const float4 bv = *(const float4*)(Bb + (size_t)(kt + bk) * ldb + bn);

        __syncthreads();   // previous iteration's LDS reads complete
        *(float4*)&As[ar][ak] = av;
        Bst[bn + 0][bk] = bv.x;
        Bst[bn + 1][bk] = bv.y;
        Bst[bn + 2][bk] = bv.z;
        Bst[bn + 3][bk] = bv.w;
        __syncthreads();

        #pragma unroll
        for (int kk = 0; kk < 16; kk += 2) {
            float2 af[4], bf[4];
            #pragma unroll
            for (int j = 0; j < 4; ++j) af[j] = *(const float2*)&As[ty + 16 * j][kk];
            #pragma unroll
            for (int i = 0; i < 4; ++i) bf[i] = *(const float2*)&Bst[tx + 16 * i][kk];
            #pragma unroll
            for (int j = 0; j < 4; ++j)
                #pragma unroll
                for (int i = 0; i < 4; ++i)
                    acc[j][i] += af[j].x * bf[i].x + af[j].y * bf[i].y;
        }
    }

    // epilogue
    float* Cb;
    if constexpr (PERM_C) {
        const int b = row0 >> 11;
        const int s0 = row0 & 2047;
        Cb = C + ((size_t)(b * NHEAD + blockIdx.x) * SEQ + s0) * DK;
    } else {
        Cb = C + (size_t)row0 * ldc + col0;
    }
    #pragma unroll
    for (int j = 0; j < 4; ++j) {
        const int rl = ty + 16 * j;
        #pragma unroll
        for (int i = 0; i < 4; ++i) {
            const int cl = tx + 16 * i;
            float v = acc[j][i];
            if constexpr (HAS_BIAS) v += bias[col0 + cl];
            if constexpr (DO_RELU)  v = fmaxf(v, 0.f);
            if constexpr (HAS_RES)  v += res[(size_t)(row0 + rl) * ldc + col0 + cl];
            if constexpr (PERM_C)   Cb[rl * DK + cl] = v;
            else                    Cb[(size_t)rl * ldc + cl] = v;
        }
    }
}

// ---------------------------------------------------------------------------
// Flash attention: one block per (b,h, 64-row Q tile). Online softmax.
// K-tile LDS buffer is reused for P (saves 17 KB). O overwrites q in place.
// ---------------------------------------------------------------------------
__global__ __launch_bounds__(256)
void attn_kernel(float* __restrict__ qbuf, const float* __restrict__ kbuf,
                 const float* __restrict__ vbuf)
{
    __shared__ float Qs[64][68];   // [row][d], pre-scaled by 1/sqrt(DK)
    __shared__ float KP[64][68];   // K tile [t][d]  ... reused as P [row][t]
    __shared__ float Vt[64][68];   // V transposed [k][t]

    const int tid = threadIdx.x;
    const int tx = tid & 15;
    const int ty = tid >> 4;
    const int bh = blockIdx.y;             // b*8 + h
    const int s0 = blockIdx.x * 64;

    float* qptr = qbuf + (size_t)bh * (SEQ * DK) + (size_t)s0 * DK;
    const float* kptr = kbuf + (size_t)bh * (SEQ * DK);
    const float* vptr = vbuf + (size_t)bh * (SEQ * DK);

    // load Q tile (scaled)
    #pragma unroll
    for (int rep = 0; rep < 4; ++rep) {
        const int idx = rep * 256 + tid;
        const int r = idx >> 4, d4 = (idx & 15) << 2;
        float4 v = *(const float4*)(qptr + r * DK + d4);
        v.x *= 0.125f; v.y *= 0.125f; v.z *= 0.125f; v.w *= 0.125f;
        *(float4*)&Qs[r][d4] = v;
    }

    float o[4][4], m[4], l[4];
    #pragma unroll
    for (int j = 0; j < 4; ++j) {
        m[j] = -INFINITY; l[j] = 0.f;
        #pragma unroll
        for (int i = 0; i < 4; ++i) o[j][i] = 0.f;
    }

    for (int t0 = 0; t0 < SEQ; t0 += 64) {
        __syncthreads();   // previous PV reads of KP/Vt done (covers Qs on iter 0)
        #pragma unroll
        for (int rep = 0; rep < 4; ++rep) {
            const int idx = rep * 256 + tid;
            const int r = idx >> 4, d4 = (idx & 15) << 2;
            *(float4*)&KP[r][d4] = *(const float4*)(kptr + (size_t)(t0 + r) * DK + d4);
            const float4 vv = *(const float4*)(vptr + (size_t)(t0 + r) * DK + d4);
            Vt[d4 + 0][r] = vv.x;
            Vt[d4 + 1][r] = vv.y;
            Vt[d4 + 2][r] = vv.z;
            Vt[d4 + 3][r] = vv.w;
        }
        __syncthreads();

        // S = Q K^T  (pre-scaled)
        float s[4][4];
        #pragma unroll
        for (int j = 0; j < 4; ++j)
            #pragma unroll
            for (int i = 0; i < 4; ++i) s[j][i] = 0.f;
        #pragma unroll 4
        for (int d = 0; d < 64; d += 2) {
            float2 qf[4], kf[4];
            #pragma unroll
            for (int j = 0; j < 4; ++j) qf[j] = *(const float2*)&Qs[ty + 16 * j][d];
            #pragma unroll
            for (int i = 0; i < 4; ++i) kf[i] = *(const float2*)&KP[tx + 16 * i][d];
            #pragma unroll
            for (int j = 0; j < 4; ++j)
                #pragma unroll
                for (int i = 0; i < 4; ++i)
                    s[j][i] += qf[j].x * kf[i].x + qf[j].y * kf[i].y;
        }

        // online softmax update (row stats across the 16 tx lanes)
        float p[4][4];
        #pragma unroll
        for (int j = 0; j < 4; ++j) {
            float mt = fmaxf(fmaxf(s[j][0], s[j][1]), fmaxf(s[j][2], s[j][3]));
            mt = fmaxf(mt, __shfl_xor(mt, 1, 16));
            mt = fmaxf(mt, __shfl_xor(mt, 2, 16));
            mt = fmaxf(mt, __shfl_xor(mt, 4, 16));
            mt = fmaxf(mt, __shfl_xor(mt, 8, 16));
            const float mnew = fmaxf(m[j], mt);
            const float alpha = __expf(m[j] - mnew);   // first tile: exp(-inf)=0
            m[j] = mnew;
            float rs = 0.f;
            #pragma unroll
            for (int i = 0; i < 4; ++i) { p[j][i] = __expf(s[j][i] - mnew); rs += p[j][i]; }
            rs += __shfl_xor(rs, 1, 16);
            rs += __shfl_xor(rs, 2, 16);
            rs += __shfl_xor(rs, 4, 16);
            rs += __shfl_xor(rs, 8, 16);
            l[j] = l[j] * alpha + rs;
            #pragma unroll
            for (int i = 0; i < 4; ++i) o[j][i] *= alpha;
        }

        __syncthreads();   // all QK reads of KP done -> safe to overwrite with P
        #pragma unroll
        for (int j = 0; j < 4; ++j)
            #pragma unroll
            for (int i = 0; i < 4; ++i)
                KP[ty + 16 * j][tx + 16 * i] = p[j][i];
        __syncthreads();

        // O += P V
        #pragma unroll 4
        for (int t = 0; t < 64; t += 2) {
            float2 pf[4], vf[4];
            #pragma unroll
            for (int j = 0; j < 4; ++j) pf[j] = *(const float2*)&KP[ty + 16 * j][t];
            #pragma unroll
            for (int i = 0; i < 4; ++i) vf[i] = *(const float2*)&Vt[tx + 16 * i][t];
            #pragma unroll
            for (int j = 0; j < 4; ++j)
                #pragma unroll
                for (int i = 0; i < 4; ++i)
                    o[j][i] += pf[j].x * vf[i].x + pf[j].y * vf[i].y;
        }
    }

    // normalize and write O over the q buffer (this block owns these rows)
    #pragma unroll
    for (int j = 0; j < 4; ++j) {
        const float inv = 1.f / l[j];
        #pragma unroll
        for (int i = 0; i < 4; ++i)
            qptr[(ty + 16 * j) * DK + tx + 16 * i] = o[j][i] * inv;
    }
}

// ---------------------------------------------------------------------------
// LayerNorm over rows of 512. One wave per row, 4 rows per block.
// ---------------------------------------------------------------------------
__global__ __launch_bounds__(256)
void ln_kernel(const float* __restrict__ in, const float* __restrict__ g,
               const float* __restrict__ bb, float* __restrict__ out)
{
    const int row = blockIdx.x * 4 + (threadIdx.x >> 6);
    const int lane = threadIdx.x & 63;
    const float* p = in + (size_t)row * D_MODEL;

    const float4 a = *(const float4*)(p + lane * 4);
    const float4 c = *(const float4*)(p + 256 + lane * 4);
    float sum = a.x + a.y + a.z + a.w + c.x + c.y + c.z + c.w;
    float sq  = a.x * a.x + a.y * a.y + a.z * a.z + a.w * a.w
              + c.x * c.x + c.y * c.y + c.z * c.z + c.w * c.w;
    #pragma unroll
    for (int msk = 1; msk < 64; msk <<= 1) {
        sum += __shfl_xor(sum, msk, 64);
        sq  += __shfl_xor(sq,  msk, 64);
    }
    const float mean = sum * (1.f / 512.f);
    const float var  = sq * (1.f / 512.f) - mean * mean;
    const float rs   = rsqrtf(var + 1e-5f);

    const float4 g0 = *(const float4*)(g + lane * 4);
    const float4 g1 = *(const float4*)(g + 256 + lane * 4);
    const float4 b0 = *(const float4*)(bb + lane * 4);
    const float4 b1 = *(const float4*)(bb + 256 + lane * 4);

    float4 o0, o1;
    o0.x = (a.x - mean) * rs * g0.x + b0.x;
    o0.y = (a.y - mean) * rs * g0.y + b0.y;
    o0.z = (a.z - mean) * rs * g0.z + b0.z;
    o0.w = (a.w - mean) * rs * g0.w + b0.w;
    o1.x = (c.x - mean) * rs * g1.x + b1.x;
    o1.y = (c.y - mean) * rs * g1.y + b1.y;
    o1.z = (c.z - mean) * rs * g1.z + b1.z;
    o1.w = (c.w - mean) * rs * g1.w + b1.w;
    *(float4*)(out + (size_t)row * D_MODEL + lane * 4) = o0;
    *(float4*)(out + (size_t)row * D_MODEL + 256 + lane * 4) = o1;
}

// ---------------------------------------------------------------------------
extern "C" void kernel_launch(void* const* d_in, const int* in_sizes, int n_in,
                              void* d_out, int out_size, void* d_ws, size_t ws_size,
                              hipStream_t stream)
{
    (void)in_sizes; (void)n_in; (void)out_size;

    const float* x    = (const float*)d_in[0];
    const float* wq   = (const float*)d_in[1];
    const float* wk   = (const float*)d_in[2];
    const float* wv   = (const float*)d_in[3];
    const float* wo   = (const float*)d_in[4];
    const float* w1   = (const float*)d_in[5];
    const float* b1   = (const float*)d_in[6];
    const float* w2   = (const float*)d_in[7];
    const float* b2   = (const float*)d_in[8];
    const float* ln1g = (const float*)d_in[9];
    const float* ln1b = (const float*)d_in[10];
    const float* ln2g = (const float*)d_in[11];
    const float* ln2b = (const float*)d_in[12];
    float* out = (float*)d_out;

    // ---- workspace layout (floats) ----
    // [0 .. NQKV)       qb   (q proj, then attention O in place)
    // [NQKV .. 2N)      kb   (k proj; later y = pre-LN1; later y2 = pre-LN2)
    // [2N .. 3N)        vb   (v proj)
    // [3N .. )          hid  (FFN hidden, chunked rows x DFF)
    // x1 (post-LN1) lives in d_out, fully consumed by step 6 before step 7
    // overwrites d_out with the final result.
    const size_t NQKV = (size_t)MROWS * D_MODEL;      // 8388608 floats
    float* qb  = (float*)d_ws;
    float* kb  = qb + NQKV;
    float* vb  = kb + NQKV;
    float* hid = vb + NQKV;
    float* x1  = out;   // scratch use of d_out
    float* y   = kb;    // k dead after attention
    float* y2  = kb;    // y dead after LN1

    // FFN row-chunk sized from remaining workspace (deterministic in ws_size)
    const size_t used = 3 * NQKV * sizeof(float);
    size_t avail = (ws_size > used) ? (ws_size - used) : 0;
    int chunk = (int)(avail / ((size_t)DFF * sizeof(float)));
    chunk &= ~63;                       // multiple of 64 rows
    if (chunk > MROWS) chunk = MROWS;
    if (chunk < 64)    chunk = 64;      // minimum viable; ws must cover this

    const dim3 blk(256);

    // 1) q, k, v projections (per-head output layout)
    gemm_kernel<false, true, false, false, false>
        <<<dim3(NHEAD, MROWS / 64), blk, 0, stream>>>(x, wq, nullptr, nullptr, qb,
                                                      D_MODEL, DK, DK, D_MODEL);
    gemm_kernel<false, true, false, false, false>
        <<<dim3(NHEAD, MROWS / 64), blk, 0, stream>>>(x, wk, nullptr, nullptr, kb,
                                                      D_MODEL, DK, DK, D_MODEL);
    gemm_kernel<false, true, false, false, false>
        <<<dim3(NHEAD, MROWS / 64), blk, 0, stream>>>(x, wv, nullptr, nullptr, vb,
                                                      D_MODEL, DK, DK, D_MODEL);

    // 2) flash attention, O in-place over qb
    attn_kernel<<<dim3(SEQ / 64, BATCH * NHEAD), blk, 0, stream>>>(qb, kb, vb);

    // 3) y = concat(O) @ wo + x     (y aliases kb)
    gemm_kernel<true, false, false, false, true>
        <<<dim3(D_MODEL / 64, MROWS / 64), blk, 0, stream>>>(qb, wo, nullptr, x, y,
                                                             DK, D_MODEL, D_MODEL, D_MODEL);
    // 4) x1 = LN1(y)                (x1 lives in d_out)
    ln_kernel<<<MROWS / 4, blk, 0, stream>>>(y, ln1g, ln1b, x1);

    // 5+6) FFN, chunked over rows to fit workspace
    for (int r0 = 0; r0 < MROWS; r0 += chunk) {
        const int rows = (r0 + chunk <= MROWS) ? chunk : (MROWS - r0);
        // hidden = relu(x1[r0:r0+rows] @ w1 + b1)
        gemm_kernel<false, false, true, true, false>
            <<<dim3(DFF / 64, rows / 64), blk, 0, stream>>>(x1 + (size_t)r0 * D_MODEL,
                                                            w1, b1, nullptr, hid,
                                                            D_MODEL, DFF, DFF, D_MODEL);
        // y2[r0:] = hidden @ w2 + b2 + x1[r0:]
        gemm_kernel<false, false, true, false, true>
            <<<dim3(D_MODEL / 64, rows / 64), blk, 0, stream>>>(hid, w2, b2,
                                                                x1 + (size_t)r0 * D_MODEL,
                                                                y2 + (size_t)r0 * D_MODEL,
                                                                DFF, D_MODEL, D_MODEL, DFF);
    }

    // 7) out = LN2(y2)              (overwrites the x1 scratch in d_out)
    ln_kernel<<<MROWS / 4, blk, 0, stream>>>(y2, ln2g, ln2b, out);
}

// Round 3
// 595.413 us; speedup vs baseline: 5.4797x; 5.4797x over previous
//
#include <hip/hip_runtime.h>
#include <hip/hip_bf16.h>
#include <math.h>

// ---------------------------------------------------------------------------
// EncoderLayer, bf16-MFMA mixed precision for MI355X (gfx950).
// B=8, S=2048, D=512, H=8, DK=64, DFF=2048, M=16384.
// All GEMMs + attention matmuls: mfma_f32_16x16x32_bf16 (fp32 accumulate).
// Softmax, LayerNorm, residuals, bias: fp32.
// ---------------------------------------------------------------------------

#define D_MODEL 512
#define NHEAD   8
#define DKH     64
#define SEQ     2048
#define BATCH   8
#define DFF     2048
#define MROWS   (BATCH * SEQ)          // 16384

typedef __bf16 bf16x8 __attribute__((ext_vector_type(8)));
typedef float  f32x4  __attribute__((ext_vector_type(4)));

__device__ __forceinline__ unsigned short f2bf(float f) {
    union { float f; unsigned u; } v; v.f = f;
    return (unsigned short)((v.u + 0x7FFFu + ((v.u >> 16) & 1u)) >> 16);
}

__device__ __forceinline__ f32x4 mfma16(bf16x8 a, bf16x8 b, f32x4 c) {
    return __builtin_amdgcn_mfma_f32_16x16x32_bf16(a, b, c, 0, 0, 0);
}

// ---------------------------------------------------------------------------
// bf16 MFMA GEMM: C[M,N] = A[M,K] * Bt[N,K]^T  (+bias, +relu, +fp32 residual)
// 128x128 tile, BK=32, 256 threads = 4 waves, each wave a 64x64 quadrant
// (4x4 fragments of 16x16x32). LDS stride 40 (padded): conflict-free b128.
// AF32: A is fp32, cast to bf16 during staging. OUTF32: fp32 out else bf16.
// ---------------------------------------------------------------------------
template<bool AF32, bool BIAS, bool RELU, bool RES, bool OUTF32>
__global__ __launch_bounds__(256)
void mfma_gemm(const void* __restrict__ Av, const unsigned short* __restrict__ Bt,
               const float* __restrict__ bias, const float* __restrict__ res,
               void* __restrict__ Cv, int Kdim, int N)
{
    __shared__ unsigned short As[128][40];
    __shared__ unsigned short Bs[128][40];

    const int tid  = threadIdx.x;
    const int lane = tid & 63;
    const int w    = tid >> 6;
    const int mq   = (w >> 1) << 6;    // wave quadrant row
    const int nq   = (w & 1) << 6;     // wave quadrant col
    const int lrow = lane & 15;
    const int g    = lane >> 4;
    const int lk   = g << 3;           // k offset of this lane's 8 elems

    const int row0 = blockIdx.y << 7;
    const int col0 = blockIdx.x << 7;

    const int sr = tid >> 1;           // staging row 0..127
    const int sk = (tid & 1) << 4;     // staging k offset 0/16

    const f32x4 zero = {0.f, 0.f, 0.f, 0.f};
    f32x4 acc[4][4];
    #pragma unroll
    for (int i = 0; i < 4; ++i)
        #pragma unroll
        for (int j = 0; j < 4; ++j) acc[i][j] = zero;

    for (int kt = 0; kt < Kdim; kt += 32) {
        unsigned int sA[8];
        if constexpr (AF32) {
            const float* ap = (const float*)Av + (size_t)(row0 + sr) * Kdim + kt + sk;
            const float4 f0 = *(const float4*)(ap + 0);
            const float4 f1 = *(const float4*)(ap + 4);
            const float4 f2 = *(const float4*)(ap + 8);
            const float4 f3 = *(const float4*)(ap + 12);
            unsigned short* u = (unsigned short*)sA;
            u[0]=f2bf(f0.x); u[1]=f2bf(f0.y); u[2]=f2bf(f0.z); u[3]=f2bf(f0.w);
            u[4]=f2bf(f1.x); u[5]=f2bf(f1.y); u[6]=f2bf(f1.z); u[7]=f2bf(f1.w);
            u[8]=f2bf(f2.x); u[9]=f2bf(f2.y); u[10]=f2bf(f2.z); u[11]=f2bf(f2.w);
            u[12]=f2bf(f3.x); u[13]=f2bf(f3.y); u[14]=f2bf(f3.z); u[15]=f2bf(f3.w);
        } else {
            const unsigned short* ap =
                (const unsigned short*)Av + (size_t)(row0 + sr) * Kdim + kt + sk;
            *(uint4*)&sA[0] = *(const uint4*)ap;
            *(uint4*)&sA[4] = *(const uint4*)(ap + 8);
        }
        uint4 b0, b1;
        {
            const unsigned short* bp = Bt + (size_t)(col0 + sr) * Kdim + kt + sk;
            b0 = *(const uint4*)bp;
            b1 = *(const uint4*)(bp + 8);
        }
        __syncthreads();   // previous iteration's frag reads complete
        *(uint4*)&As[sr][sk]     = *(uint4*)&sA[0];
        *(uint4*)&As[sr][sk + 8] = *(uint4*)&sA[4];
        *(uint4*)&Bs[sr][sk]     = b0;
        *(uint4*)&Bs[sr][sk + 8] = b1;
        __syncthreads();

        bf16x8 af[4], bfv[4];
        #pragma unroll
        for (int mf = 0; mf < 4; ++mf)
            af[mf] = *(const bf16x8*)&As[mq + mf * 16 + lrow][lk];
        #pragma unroll
        for (int nf = 0; nf < 4; ++nf)
            bfv[nf] = *(const bf16x8*)&Bs[nq + nf * 16 + lrow][lk];
        #pragma unroll
        for (int mf = 0; mf < 4; ++mf)
            #pragma unroll
            for (int nf = 0; nf < 4; ++nf)
                acc[mf][nf] = mfma16(af[mf], bfv[nf], acc[mf][nf]);
    }

    // epilogue: C/D layout col = lane&15, row = 4*(lane>>4)+reg
    const int orow = row0 + mq + g * 4;
    const int ocol = col0 + nq + lrow;
    #pragma unroll
    for (int mf = 0; mf < 4; ++mf) {
        #pragma unroll
        for (int nf = 0; nf < 4; ++nf) {
            const int cc = ocol + nf * 16;
            float bv = 0.f;
            if constexpr (BIAS) bv = bias[cc];
            #pragma unroll
            for (int r = 0; r < 4; ++r) {
                const int rr = orow + mf * 16 + r;
                float v = acc[mf][nf][r];
                if constexpr (BIAS) v += bv;
                if constexpr (RELU) v = fmaxf(v, 0.f);
                if constexpr (RES)  v += res[(size_t)rr * N + cc];
                if constexpr (OUTF32) ((float*)Cv)[(size_t)rr * N + cc] = v;
                else ((unsigned short*)Cv)[(size_t)rr * N + cc] = f2bf(v);
            }
        }
    }
}

// ---------------------------------------------------------------------------
// bf16 MFMA flash attention. Block = 4 waves, 64 Q-rows (16 per wave),
// KV tiles of 64. Q fragments live in registers for the whole kernel.
// q/k/v layout: [M][512] bf16, col = h*64 + c. O overwrites q in place.
// ---------------------------------------------------------------------------
__global__ __launch_bounds__(256)
void mfma_attn(unsigned short* __restrict__ qb, const unsigned short* __restrict__ kb,
               const unsigned short* __restrict__ vb)
{
    __shared__ unsigned short Ks[64][72];   // K tile [kv][dk]
    __shared__ unsigned short Vt[64][72];   // V transposed [dk][kv]
    __shared__ unsigned short Ps[64][72];   // P [qrow][kv], 16 rows per wave

    const int tid  = threadIdx.x;
    const int lane = tid & 63;
    const int w    = tid >> 6;
    const int lrow = lane & 15;
    const int g    = lane >> 4;
    const int lk   = g << 3;

    const int bh = blockIdx.y;
    const int b  = bh >> 3, h = bh & 7;
    const int s0 = blockIdx.x << 6;

    const size_t qoff  = ((size_t)(b * SEQ + s0)) * D_MODEL + h * DKH;
    const unsigned short* kbase = kb + ((size_t)(b * SEQ)) * D_MODEL + h * DKH;
    const unsigned short* vbase = vb + ((size_t)(b * SEQ)) * D_MODEL + h * DKH;

    // Q fragments (rows w*16+lrow), pre-scaled by 0.125 via the weight pack
    bf16x8 qf[2];
    {
        const unsigned short* qp = qb + qoff + (size_t)(w * 16 + lrow) * D_MODEL;
        qf[0] = *(const bf16x8*)(qp + lk);
        qf[1] = *(const bf16x8*)(qp + 32 + lk);
    }

    const f32x4 zero = {0.f, 0.f, 0.f, 0.f};
    f32x4 oacc[4];                    // [dk frag]; elem r = q-row g*4+r
    float mrun[4], lrun[4];
    #pragma unroll
    for (int i = 0; i < 4; ++i) { oacc[i] = zero; mrun[i] = -INFINITY; lrun[i] = 0.f; }

    const int kr = tid >> 2, kc = (tid & 3) << 4;   // K staging: row, col-seg
    const int vr = tid & 63, vc = (tid >> 6) << 4;  // V staging: row, col-seg

    for (int t0 = 0; t0 < SEQ; t0 += 64) {
        // load K and V tile into regs
        const unsigned short* kp = kbase + (size_t)(t0 + kr) * D_MODEL + kc;
        const uint4 k0 = *(const uint4*)kp;
        const uint4 k1 = *(const uint4*)(kp + 8);
        const unsigned short* vp = vbase + (size_t)(t0 + vr) * D_MODEL + vc;
        const uint4 v0 = *(const uint4*)vp;
        const uint4 v1 = *(const uint4*)(vp + 8);

        __syncthreads();   // previous tile's LDS reads complete
        *(uint4*)&Ks[kr][kc]     = k0;
        *(uint4*)&Ks[kr][kc + 8] = k1;
        const unsigned short* vu0 = (const unsigned short*)&v0;
        const unsigned short* vu1 = (const unsigned short*)&v1;
        #pragma unroll
        for (int j = 0; j < 8; ++j) Vt[vc + j][vr]     = vu0[j];
        #pragma unroll
        for (int j = 0; j < 8; ++j) Vt[vc + 8 + j][vr] = vu1[j];
        __syncthreads();

        // S = Q K^T : per wave 16x64, acc elem r -> q-row g*4+r, col nf*16+lrow
        f32x4 sacc[4];
        #pragma unroll
        for (int nf = 0; nf < 4; ++nf) sacc[nf] = zero;
        #pragma unroll
        for (int kk = 0; kk < 2; ++kk) {
            #pragma unroll
            for (int nf = 0; nf < 4; ++nf) {
                const bf16x8 kf = *(const bf16x8*)&Ks[nf * 16 + lrow][kk * 32 + lk];
                sacc[nf] = mfma16(qf[kk], kf, sacc[nf]);
            }
        }

        // online softmax (row stats across the 16-lane col groups)
        float pj[4][4];   // [r][nf]
        #pragma unroll
        for (int r = 0; r < 4; ++r) {
            float mt = fmaxf(fmaxf(sacc[0][r], sacc[1][r]),
                             fmaxf(sacc[2][r], sacc[3][r]));
            mt = fmaxf(mt, __shfl_xor(mt, 1, 16));
            mt = fmaxf(mt, __shfl_xor(mt, 2, 16));
            mt = fmaxf(mt, __shfl_xor(mt, 4, 16));
            mt = fmaxf(mt, __shfl_xor(mt, 8, 16));
            const float mnew = fmaxf(mrun[r], mt);
            const float alpha = __expf(mrun[r] - mnew);   // first tile: 0
            mrun[r] = mnew;
            float rs = 0.f;
            #pragma unroll
            for (int nf = 0; nf < 4; ++nf) {
                const float p = __expf(sacc[nf][r] - mnew);
                pj[r][nf] = p; rs += p;
            }
            rs += __shfl_xor(rs, 1, 16);
            rs += __shfl_xor(rs, 2, 16);
            rs += __shfl_xor(rs, 4, 16);
            rs += __shfl_xor(rs, 8, 16);
            lrun[r] = lrun[r] * alpha + rs;
            #pragma unroll
            for (int nf = 0; nf < 4; ++nf) oacc[nf][r] *= alpha;
        }

        // P -> LDS (bf16), per-wave private rows: no cross-wave barrier needed
        #pragma unroll
        for (int r = 0; r < 4; ++r)
            #pragma unroll
            for (int nf = 0; nf < 4; ++nf)
                Ps[w * 16 + g * 4 + r][nf * 16 + lrow] = f2bf(pj[r][nf]);

        // O += P V
        #pragma unroll
        for (int kk = 0; kk < 2; ++kk) {
            const bf16x8 pf = *(const bf16x8*)&Ps[w * 16 + lrow][kk * 32 + lk];
            #pragma unroll
            for (int nf = 0; nf < 4; ++nf) {
                const bf16x8 vf = *(const bf16x8*)&Vt[nf * 16 + lrow][kk * 32 + lk];
                oacc[nf] = mfma16(pf, vf, oacc[nf]);
            }
        }
    }

    // normalize, write O bf16 in place over q (this block owns these rows)
    unsigned short* op = qb + qoff;
    #pragma unroll
    for (int r = 0; r < 4; ++r) {
        const float inv = 1.f / lrun[r];
        #pragma unroll
        for (int nf = 0; nf < 4; ++nf)
            op[(size_t)(w * 16 + g * 4 + r) * D_MODEL + nf * 16 + lrow] =
                f2bf(oacc[nf][r] * inv);
    }
}

// ---------------------------------------------------------------------------
// LayerNorm rows of 512; one wave per row. Optional bf16 secondary output.
// Safe in-place (outf == in): each wave reads its row fully before writing.
// ---------------------------------------------------------------------------
template<bool WB>
__global__ __launch_bounds__(256)
void ln_kernel(const float* __restrict__ in, const float* __restrict__ gg,
               const float* __restrict__ bb, float* __restrict__ outf,
               unsigned short* __restrict__ outb)
{
    const int row = blockIdx.x * 4 + (threadIdx.x >> 6);
    const int lane = threadIdx.x & 63;
    const float* p = in + (size_t)row * D_MODEL;

    const float4 a = *(const float4*)(p + lane * 4);
    const float4 c = *(const float4*)(p + 256 + lane * 4);
    float sum = a.x + a.y + a.z + a.w + c.x + c.y + c.z + c.w;
    float sq  = a.x*a.x + a.y*a.y + a.z*a.z + a.w*a.w
              + c.x*c.x + c.y*c.y + c.z*c.z + c.w*c.w;
    #pragma unroll
    for (int msk = 1; msk < 64; msk <<= 1) {
        sum += __shfl_xor(sum, msk, 64);
        sq  += __shfl_xor(sq,  msk, 64);
    }
    const float mean = sum * (1.f / 512.f);
    const float var  = sq * (1.f / 512.f) - mean * mean;
    const float rs   = rsqrtf(var + 1e-5f);

    const float4 g0 = *(const float4*)(gg + lane * 4);
    const float4 g1 = *(const float4*)(gg + 256 + lane * 4);
    const float4 b0 = *(const float4*)(bb + lane * 4);
    const float4 b1 = *(const float4*)(bb + 256 + lane * 4);

    float4 o0, o1;
    o0.x = (a.x - mean) * rs * g0.x + b0.x;
    o0.y = (a.y - mean) * rs * g0.y + b0.y;
    o0.z = (a.z - mean) * rs * g0.z + b0.z;
    o0.w = (a.w - mean) * rs * g0.w + b0.w;
    o1.x = (c.x - mean) * rs * g1.x + b1.x;
    o1.y = (c.y - mean) * rs * g1.y + b1.y;
    o1.z = (c.z - mean) * rs * g1.z + b1.z;
    o1.w = (c.w - mean) * rs * g1.w + b1.w;
    *(float4*)(outf + (size_t)row * D_MODEL + lane * 4) = o0;
    *(float4*)(outf + (size_t)row * D_MODEL + 256 + lane * 4) = o1;
    if constexpr (WB) {
        const unsigned int q0 = f2bf(o0.x) | ((unsigned)f2bf(o0.y) << 16);
        const unsigned int q1 = f2bf(o0.z) | ((unsigned)f2bf(o0.w) << 16);
        const unsigned int q2 = f2bf(o1.x) | ((unsigned)f2bf(o1.y) << 16);
        const unsigned int q3 = f2bf(o1.z) | ((unsigned)f2bf(o1.w) << 16);
        uint2 pa; pa.x = q0; pa.y = q1;
        uint2 pb; pb.x = q2; pb.y = q3;
        *(uint2*)(outb + (size_t)row * D_MODEL + lane * 4) = pa;
        *(uint2*)(outb + (size_t)row * D_MODEL + 256 + lane * 4) = pb;
    }
}

// ---------------------------------------------------------------------------
// Weight packing: per-head q/k/v weights -> [N=512][K=512] bf16, q scaled 1/8.
// ---------------------------------------------------------------------------
__global__ __launch_bounds__(256)
void pack_qkv(const float* __restrict__ wq, const float* __restrict__ wk,
              const float* __restrict__ wv, unsigned short* __restrict__ Wq,
              unsigned short* __restrict__ Wk, unsigned short* __restrict__ Wv)
{
    const int idx = blockIdx.x * 256 + threadIdx.x;   // n*512 + d
    const int n = idx >> 9, d = idx & 511;
    const int h = n >> 6, c = n & 63;
    const size_t src = ((size_t)h * 512 + d) * 64 + c;
    Wq[idx] = f2bf(wq[src] * 0.125f);
    Wk[idx] = f2bf(wk[src]);
    Wv[idx] = f2bf(wv[src]);
}

// transpose-cast: in fp32 [K][N] -> out bf16 [N][K]
__global__ __launch_bounds__(256)
void pack_t(const float* __restrict__ in, unsigned short* __restrict__ out,
            int K, int N)
{
    const int idx = blockIdx.x * 256 + threadIdx.x;
    const int n = idx / K, k = idx % K;
    out[idx] = f2bf(in[(size_t)k * N + n]);
}

// ---------------------------------------------------------------------------
extern "C" void kernel_launch(void* const* d_in, const int* in_sizes, int n_in,
                              void* d_out, int out_size, void* d_ws, size_t ws_size,
                              hipStream_t stream)
{
    (void)in_sizes; (void)n_in; (void)out_size;

    const float* x    = (const float*)d_in[0];
    const float* wq   = (const float*)d_in[1];
    const float* wk   = (const float*)d_in[2];
    const float* wv   = (const float*)d_in[3];
    const float* wo   = (const float*)d_in[4];
    const float* w1   = (const float*)d_in[5];
    const float* b1   = (const float*)d_in[6];
    const float* w2   = (const float*)d_in[7];
    const float* b2   = (const float*)d_in[8];
    const float* ln1g = (const float*)d_in[9];
    const float* ln1b = (const float*)d_in[10];
    const float* ln2g = (const float*)d_in[11];
    const float* ln2b = (const float*)d_in[12];
    float* out = (float*)d_out;

    // ---- workspace layout (bytes). Fixed footprint ~90.7 MB. ----
    const size_t SZ = (size_t)MROWS * D_MODEL * 2;    // one [M][512] bf16 = 16 MB
    unsigned char* base = (unsigned char*)d_ws;
    unsigned short* q_bf = (unsigned short*)(base);            // -> O in place
    unsigned short* k_bf = (unsigned short*)(base + SZ);
    unsigned short* v_bf = (unsigned short*)(base + 2 * SZ);
    float*          y    = (float*)(base + 3 * SZ);            // fp32, 2*SZ bytes
    unsigned short* Wq_t = (unsigned short*)(base + 5 * SZ);
    unsigned short* Wk_t = Wq_t + 512 * 512;
    unsigned short* Wv_t = Wk_t + 512 * 512;
    unsigned short* wo_t = Wv_t + 512 * 512;
    unsigned short* w1_t = wo_t + 512 * 512;
    unsigned short* w2_t = w1_t + 2048 * 512;
    unsigned short* hid  = w2_t + 2048 * 512;

    const size_t hid_off = (size_t)((unsigned char*)hid - base);
    const size_t avail = (ws_size > hid_off) ? (ws_size - hid_off) : 0;
    int chunk = (int)(avail / ((size_t)DFF * 2));
    chunk &= ~127;
    if (chunk > MROWS) chunk = MROWS;
    if (chunk < 128)   chunk = 128;

    float* y2 = (float*)k_bf;                  // k/v dead after attention (2*SZ)
    unsigned short* x1b = (unsigned short*)d_out;  // bf16 scratch inside d_out

    // ---- weight packing (tiny) ----
    pack_qkv<<<1024, 256, 0, stream>>>(wq, wk, wv, Wq_t, Wk_t, Wv_t);
    pack_t<<<(512 * 512) / 256, 256, 0, stream>>>(wo, wo_t, 512, 512);
    pack_t<<<(2048 * 512) / 256, 256, 0, stream>>>(w1, w1_t, 512, 2048);
    pack_t<<<(2048 * 512) / 256, 256, 0, stream>>>(w2, w2_t, 2048, 512);

    const dim3 blk(256);
    const dim3 g512(4, MROWS / 128);

    // 1) q,k,v projections (A = x fp32, cast in staging; out bf16 [M][512])
    mfma_gemm<true, false, false, false, false>
        <<<g512, blk, 0, stream>>>(x, Wq_t, nullptr, nullptr, q_bf, 512, 512);
    mfma_gemm<true, false, false, false, false>
        <<<g512, blk, 0, stream>>>(x, Wk_t, nullptr, nullptr, k_bf, 512, 512);
    mfma_gemm<true, false, false, false, false>
        <<<g512, blk, 0, stream>>>(x, Wv_t, nullptr, nullptr, v_bf, 512, 512);

    // 2) flash attention (O bf16 in place over q_bf)
    mfma_attn<<<dim3(SEQ / 64, BATCH * NHEAD), blk, 0, stream>>>(q_bf, k_bf, v_bf);

    // 3) y = O @ wo + x   (fp32 out)
    mfma_gemm<false, false, false, true, true>
        <<<g512, blk, 0, stream>>>(q_bf, wo_t, nullptr, x, y, 512, 512);

    // 4) x1 = LN1(y): fp32 in place (residual for FFN2) + bf16 into d_out
    ln_kernel<true><<<MROWS / 4, blk, 0, stream>>>(y, ln1g, ln1b, y, x1b);

    // 5+6) FFN, chunked over rows (chunk multiple of 128)
    for (int r0 = 0; r0 < MROWS; r0 += chunk) {
        const int rows = (r0 + chunk <= MROWS) ? chunk : (MROWS - r0);
        mfma_gemm<false, true, true, false, false>
            <<<dim3(DFF / 128, rows / 128), blk, 0, stream>>>(
                x1b + (size_t)r0 * D_MODEL, w1_t, b1, nullptr, hid, 512, DFF);
        mfma_gemm<false, true, false, true, true>
            <<<dim3(4, rows / 128), blk, 0, stream>>>(
                hid, w2_t, b2, y + (size_t)r0 * D_MODEL,
                y2 + (size_t)r0 * D_MODEL, DFF, 512);
    }

    // 7) out = LN2(y2)
    ln_kernel<false><<<MROWS / 4, blk, 0, stream>>>(y2, ln2g, ln2b, out, nullptr);
}

// Round 4
// 533.070 us; speedup vs baseline: 6.1206x; 1.1169x over previous
//
#include <hip/hip_runtime.h>
#include <hip/hip_bf16.h>
#include <math.h>

// ---------------------------------------------------------------------------
// EncoderLayer, bf16-MFMA mixed precision for MI355X (gfx950).
// B=8, S=2048, D=512, H=8, DK=64, DFF=2048, M=16384.
// All GEMMs + attention matmuls: mfma_f32_16x16x32_bf16 (fp32 accumulate).
// Softmax (exp2 domain), LayerNorm, residuals, bias: fp32.
// Round-4 changes: fused QKV GEMM into [M][1536]; attention QBLK=128 with
// 8 waves + K/V register prefetch; GEMM register prefetch; v_exp_f32 softmax.
// ---------------------------------------------------------------------------

#define D_MODEL 512
#define NHEAD   8
#define DKH     64
#define SEQ     2048
#define BATCH   8
#define DFF     2048
#define MROWS   (BATCH * SEQ)          // 16384
#define QKVLD   1536                   // fused q|k|v row stride

typedef __bf16 bf16x8 __attribute__((ext_vector_type(8)));
typedef float  f32x4  __attribute__((ext_vector_type(4)));

__device__ __forceinline__ unsigned short f2bf(float f) {
    union { float f; unsigned u; } v; v.f = f;
    return (unsigned short)((v.u + 0x7FFFu + ((v.u >> 16) & 1u)) >> 16);
}

__device__ __forceinline__ float fexp2(float x) {   // raw v_exp_f32 (2^x)
    float r; asm("v_exp_f32 %0, %1" : "=v"(r) : "v"(x)); return r;
}

__device__ __forceinline__ f32x4 mfma16(bf16x8 a, bf16x8 b, f32x4 c) {
    return __builtin_amdgcn_mfma_f32_16x16x32_bf16(a, b, c, 0, 0, 0);
}

// ---------------------------------------------------------------------------
// bf16 MFMA GEMM: C[M,N] = A[M,K] * Bt[N,K]^T  (+bias, +relu, +fp32 residual)
// 128x128 tile, BK=32, 256 threads = 4 waves, each wave a 64x64 quadrant
// (4x4 fragments of 16x16x32). LDS stride 40: conflict-light b128 frag reads.
// Register prefetch: tile kt+1 global loads issued before tile kt's MFMAs.
// ---------------------------------------------------------------------------
template<bool AF32, bool BIAS, bool RELU, bool RES, bool OUTF32>
__global__ __launch_bounds__(256)
void mfma_gemm(const void* __restrict__ Av, const unsigned short* __restrict__ Bt,
               const float* __restrict__ bias, const float* __restrict__ res,
               void* __restrict__ Cv, int Kdim, int lda, int ldc)
{
    __shared__ unsigned short As[128][40];
    __shared__ unsigned short Bs[128][40];

    const int tid  = threadIdx.x;
    const int lane = tid & 63;
    const int w    = tid >> 6;
    const int mq   = (w >> 1) << 6;    // wave quadrant row
    const int nq   = (w & 1) << 6;     // wave quadrant col
    const int lrow = lane & 15;
    const int g    = lane >> 4;
    const int lk   = g << 3;           // k offset of this lane's 8 elems

    const int row0 = blockIdx.y << 7;
    const int col0 = blockIdx.x << 7;

    const int sr = tid >> 1;           // staging row 0..127
    const int sk = (tid & 1) << 4;     // staging k offset 0/16

    unsigned int sA[8];
    uint4 sB0, sB1;

    auto loadA = [&](int kt) {
        if constexpr (AF32) {
            const float* ap = (const float*)Av + (size_t)(row0 + sr) * lda + kt + sk;
            const float4 f0 = *(const float4*)(ap + 0);
            const float4 f1 = *(const float4*)(ap + 4);
            const float4 f2 = *(const float4*)(ap + 8);
            const float4 f3 = *(const float4*)(ap + 12);
            unsigned short* u = (unsigned short*)sA;
            u[0]=f2bf(f0.x); u[1]=f2bf(f0.y); u[2]=f2bf(f0.z); u[3]=f2bf(f0.w);
            u[4]=f2bf(f1.x); u[5]=f2bf(f1.y); u[6]=f2bf(f1.z); u[7]=f2bf(f1.w);
            u[8]=f2bf(f2.x); u[9]=f2bf(f2.y); u[10]=f2bf(f2.z); u[11]=f2bf(f2.w);
            u[12]=f2bf(f3.x); u[13]=f2bf(f3.y); u[14]=f2bf(f3.z); u[15]=f2bf(f3.w);
        } else {
            const unsigned short* ap =
                (const unsigned short*)Av + (size_t)(row0 + sr) * lda + kt + sk;
            *(uint4*)&sA[0] = *(const uint4*)ap;
            *(uint4*)&sA[4] = *(const uint4*)(ap + 8);
        }
    };
    auto loadB = [&](int kt) {
        const unsigned short* bp = Bt + (size_t)(col0 + sr) * Kdim + kt + sk;
        sB0 = *(const uint4*)bp;
        sB1 = *(const uint4*)(bp + 8);
    };

    const f32x4 zero = {0.f, 0.f, 0.f, 0.f};
    f32x4 acc[4][4];
    #pragma unroll
    for (int i = 0; i < 4; ++i)
        #pragma unroll
        for (int j = 0; j < 4; ++j) acc[i][j] = zero;

    loadA(0); loadB(0);

    for (int kt = 0; kt < Kdim; kt += 32) {
        __syncthreads();   // previous iteration's frag reads complete
        *(uint4*)&As[sr][sk]     = *(uint4*)&sA[0];
        *(uint4*)&As[sr][sk + 8] = *(uint4*)&sA[4];
        *(uint4*)&Bs[sr][sk]     = sB0;
        *(uint4*)&Bs[sr][sk + 8] = sB1;
        __syncthreads();

        if (kt + 32 < Kdim) { loadA(kt + 32); loadB(kt + 32); }  // in flight

        bf16x8 af[4], bfv[4];
        #pragma unroll
        for (int mf = 0; mf < 4; ++mf)
            af[mf] = *(const bf16x8*)&As[mq + mf * 16 + lrow][lk];
        #pragma unroll
        for (int nf = 0; nf < 4; ++nf)
            bfv[nf] = *(const bf16x8*)&Bs[nq + nf * 16 + lrow][lk];
        #pragma unroll
        for (int mf = 0; mf < 4; ++mf)
            #pragma unroll
            for (int nf = 0; nf < 4; ++nf)
                acc[mf][nf] = mfma16(af[mf], bfv[nf], acc[mf][nf]);
    }

    // epilogue: C/D layout col = lane&15, row = 4*(lane>>4)+reg
    const int orow = row0 + mq + g * 4;
    const int ocol = col0 + nq + lrow;
    #pragma unroll
    for (int mf = 0; mf < 4; ++mf) {
        #pragma unroll
        for (int nf = 0; nf < 4; ++nf) {
            const int cc = ocol + nf * 16;
            float bv = 0.f;
            if constexpr (BIAS) bv = bias[cc];
            #pragma unroll
            for (int r = 0; r < 4; ++r) {
                const int rr = orow + mf * 16 + r;
                float v = acc[mf][nf][r];
                if constexpr (BIAS) v += bv;
                if constexpr (RELU) v = fmaxf(v, 0.f);
                if constexpr (RES)  v += res[(size_t)rr * ldc + cc];
                if constexpr (OUTF32) ((float*)Cv)[(size_t)rr * ldc + cc] = v;
                else ((unsigned short*)Cv)[(size_t)rr * ldc + cc] = f2bf(v);
            }
        }
    }
}

// ---------------------------------------------------------------------------
// bf16 MFMA flash attention. Block = 8 waves, 128 Q-rows (16 per wave),
// KV tiles of 64, K/V register prefetch. Softmax in exp2 domain (Q weights
// carry the 1/sqrt(dk)*log2e factor). qkv layout [M][1536], q|k|v at col
// offsets 0/512/1024, per-head col h*64. O overwrites the q section.
// ---------------------------------------------------------------------------
__global__ __launch_bounds__(512)
void mfma_attn(unsigned short* __restrict__ qkv)
{
    __shared__ unsigned short Ks[64][72];    // K tile [kv][dk]
    __shared__ unsigned short Vt[64][72];    // V transposed [dk][kv]
    __shared__ unsigned short Ps[128][72];   // P [qrow][kv], 16 rows per wave

    const int tid  = threadIdx.x;
    const int lane = tid & 63;
    const int w    = tid >> 6;
    const int lrow = lane & 15;
    const int g    = lane >> 4;
    const int lk   = g << 3;

    const int bh = blockIdx.y;
    const int b  = bh >> 3, h = bh & 7;
    const int s0 = blockIdx.x << 7;

    unsigned short* qptr = qkv + ((size_t)(b * SEQ + s0)) * QKVLD + h * DKH;
    const unsigned short* kbase = qkv + ((size_t)(b * SEQ)) * QKVLD + 512 + h * DKH;
    const unsigned short* vbase = qkv + ((size_t)(b * SEQ)) * QKVLD + 1024 + h * DKH;

    // Q fragments (rows w*16+lrow), pre-scaled by 0.125*log2e via weight pack
    bf16x8 qf[2];
    {
        const unsigned short* qp = qptr + (size_t)(w * 16 + lrow) * QKVLD;
        qf[0] = *(const bf16x8*)(qp + lk);
        qf[1] = *(const bf16x8*)(qp + 32 + lk);
    }

    // staging indices
    const int kr = tid >> 3, kc = (tid & 7) << 3;   // K: 64 rows x 64 cols
    const int vr = lane,     vc = w << 3;           // V: row=lane, 8-col slab

    uint4 kreg, vreg;
    auto loadKV = [&](int t0) {
        kreg = *(const uint4*)(kbase + (size_t)(t0 + kr) * QKVLD + kc);
        vreg = *(const uint4*)(vbase + (size_t)(t0 + vr) * QKVLD + vc);
    };
    loadKV(0);

    const f32x4 zero = {0.f, 0.f, 0.f, 0.f};
    f32x4 oacc[4];                    // [dk frag]; elem r -> q-row w*16+4g+r
    float mrun[4], lrun[4];
    #pragma unroll
    for (int i = 0; i < 4; ++i) { oacc[i] = zero; mrun[i] = -INFINITY; lrun[i] = 0.f; }

    for (int t0 = 0; t0 < SEQ; t0 += 64) {
        __syncthreads();   // previous tile's LDS reads complete
        *(uint4*)&Ks[kr][kc] = kreg;
        {
            const unsigned short* vu = (const unsigned short*)&vreg;
            #pragma unroll
            for (int j = 0; j < 8; ++j) Vt[vc + j][vr] = vu[j];
        }
        __syncthreads();

        if (t0 + 64 < SEQ) loadKV(t0 + 64);   // prefetch, in flight over compute

        // S = Q K^T : per wave 16x64; acc elem r -> q-row 4g+r, col nf*16+lrow
        f32x4 sacc[4];
        #pragma unroll
        for (int nf = 0; nf < 4; ++nf) sacc[nf] = zero;
        #pragma unroll
        for (int kk = 0; kk < 2; ++kk) {
            #pragma unroll
            for (int nf = 0; nf < 4; ++nf) {
                const bf16x8 kf = *(const bf16x8*)&Ks[nf * 16 + lrow][kk * 32 + lk];
                sacc[nf] = mfma16(qf[kk], kf, sacc[nf]);
            }
        }

        // online softmax in exp2 domain (row stats across the 16-lane groups)
        float pj[4][4];   // [r][nf]
        #pragma unroll
        for (int r = 0; r < 4; ++r) {
            float mt = fmaxf(fmaxf(sacc[0][r], sacc[1][r]),
                             fmaxf(sacc[2][r], sacc[3][r]));
            mt = fmaxf(mt, __shfl_xor(mt, 1, 16));
            mt = fmaxf(mt, __shfl_xor(mt, 2, 16));
            mt = fmaxf(mt, __shfl_xor(mt, 4, 16));
            mt = fmaxf(mt, __shfl_xor(mt, 8, 16));
            const float mnew = fmaxf(mrun[r], mt);
            const float alpha = fexp2(mrun[r] - mnew);   // first tile: 2^-inf = 0
            mrun[r] = mnew;
            float rs = 0.f;
            #pragma unroll
            for (int nf = 0; nf < 4; ++nf) {
                const float p = fexp2(sacc[nf][r] - mnew);
                pj[r][nf] = p; rs += p;
            }
            rs += __shfl_xor(rs, 1, 16);
            rs += __shfl_xor(rs, 2, 16);
            rs += __shfl_xor(rs, 4, 16);
            rs += __shfl_xor(rs, 8, 16);
            lrun[r] = lrun[r] * alpha + rs;
            #pragma unroll
            for (int nf = 0; nf < 4; ++nf) oacc[nf][r] *= alpha;
        }

        // P -> LDS (bf16); wave-private rows, no extra barrier needed
        #pragma unroll
        for (int r = 0; r < 4; ++r)
            #pragma unroll
            for (int nf = 0; nf < 4; ++nf)
                Ps[w * 16 + g * 4 + r][nf * 16 + lrow] = f2bf(pj[r][nf]);

        // O += P V
        #pragma unroll
        for (int kk = 0; kk < 2; ++kk) {
            const bf16x8 pf = *(const bf16x8*)&Ps[w * 16 + lrow][kk * 32 + lk];
            #pragma unroll
            for (int nf = 0; nf < 4; ++nf) {
                const bf16x8 vf = *(const bf16x8*)&Vt[nf * 16 + lrow][kk * 32 + lk];
                oacc[nf] = mfma16(pf, vf, oacc[nf]);
            }
        }
    }

    // normalize, write O bf16 in place over q (this block owns these rows)
    #pragma unroll
    for (int r = 0; r < 4; ++r) {
        const float inv = 1.f / lrun[r];
        #pragma unroll
        for (int nf = 0; nf < 4; ++nf)
            qptr[(size_t)(w * 16 + g * 4 + r) * QKVLD + nf * 16 + lrow] =
                f2bf(oacc[nf][r] * inv);
    }
}

// ---------------------------------------------------------------------------
// LayerNorm rows of 512; one wave per row. Optional bf16 secondary output.
// Safe in-place (outf == in): each wave reads its row fully before writing.
// ---------------------------------------------------------------------------
template<bool WB>
__global__ __launch_bounds__(256)
void ln_kernel(const float* __restrict__ in, const float* __restrict__ gg,
               const float* __restrict__ bb, float* __restrict__ outf,
               unsigned short* __restrict__ outb)
{
    const int row = blockIdx.x * 4 + (threadIdx.x >> 6);
    const int lane = threadIdx.x & 63;
    const float* p = in + (size_t)row * D_MODEL;

    const float4 a = *(const float4*)(p + lane * 4);
    const float4 c = *(const float4*)(p + 256 + lane * 4);
    float sum = a.x + a.y + a.z + a.w + c.x + c.y + c.z + c.w;
    float sq  = a.x*a.x + a.y*a.y + a.z*a.z + a.w*a.w
              + c.x*c.x + c.y*c.y + c.z*c.z + c.w*c.w;
    #pragma unroll
    for (int msk = 1; msk < 64; msk <<= 1) {
        sum += __shfl_xor(sum, msk, 64);
        sq  += __shfl_xor(sq,  msk, 64);
    }
    const float mean = sum * (1.f / 512.f);
    const float var  = sq * (1.f / 512.f) - mean * mean;
    const float rs   = rsqrtf(var + 1e-5f);

    const float4 g0 = *(const float4*)(gg + lane * 4);
    const float4 g1 = *(const float4*)(gg + 256 + lane * 4);
    const float4 b0 = *(const float4*)(bb + lane * 4);
    const float4 b1 = *(const float4*)(bb + 256 + lane * 4);

    float4 o0, o1;
    o0.x = (a.x - mean) * rs * g0.x + b0.x;
    o0.y = (a.y - mean) * rs * g0.y + b0.y;
    o0.z = (a.z - mean) * rs * g0.z + b0.z;
    o0.w = (a.w - mean) * rs * g0.w + b0.w;
    o1.x = (c.x - mean) * rs * g1.x + b1.x;
    o1.y = (c.y - mean) * rs * g1.y + b1.y;
    o1.z = (c.z - mean) * rs * g1.z + b1.z;
    o1.w = (c.w - mean) * rs * g1.w + b1.w;
    *(float4*)(outf + (size_t)row * D_MODEL + lane * 4) = o0;
    *(float4*)(outf + (size_t)row * D_MODEL + 256 + lane * 4) = o1;
    if constexpr (WB) {
        uint2 pa, pb;
        pa.x = f2bf(o0.x) | ((unsigned)f2bf(o0.y) << 16);
        pa.y = f2bf(o0.z) | ((unsigned)f2bf(o0.w) << 16);
        pb.x = f2bf(o1.x) | ((unsigned)f2bf(o1.y) << 16);
        pb.y = f2bf(o1.z) | ((unsigned)f2bf(o1.w) << 16);
        *(uint2*)(outb + (size_t)row * D_MODEL + lane * 4) = pa;
        *(uint2*)(outb + (size_t)row * D_MODEL + 256 + lane * 4) = pb;
    }
}

// ---------------------------------------------------------------------------
// Weight packing: per-head q/k/v weights -> rows 0..511 / 512..1023 /
// 1024..1535 of Wqkv[1536][512] bf16. q scaled by 0.125*log2e (exp2 softmax).
// ---------------------------------------------------------------------------
__global__ __launch_bounds__(256)
void pack_qkv(const float* __restrict__ wq, const float* __restrict__ wk,
              const float* __restrict__ wv, unsigned short* __restrict__ Wqkv)
{
    const int idx = blockIdx.x * 256 + threadIdx.x;   // n*512 + d, n in 0..511
    const int n = idx >> 9, d = idx & 511;
    const int h = n >> 6, c = n & 63;
    const size_t src = ((size_t)h * 512 + d) * 64 + c;
    Wqkv[idx]               = f2bf(wq[src] * 0.18033688f);  // 0.125 * log2(e)
    Wqkv[idx + 512 * 512]   = f2bf(wk[src]);
    Wqkv[idx + 2 * 512 * 512] = f2bf(wv[src]);
}

// transpose-cast: in fp32 [K][N] -> out bf16 [N][K]
__global__ __launch_bounds__(256)
void pack_t(const float* __restrict__ in, unsigned short* __restrict__ out,
            int K, int N)
{
    const int idx = blockIdx.x * 256 + threadIdx.x;
    const int n = idx / K, k = idx % K;
    out[idx] = f2bf(in[(size_t)k * N + n]);
}

// ---------------------------------------------------------------------------
extern "C" void kernel_launch(void* const* d_in, const int* in_sizes, int n_in,
                              void* d_out, int out_size, void* d_ws, size_t ws_size,
                              hipStream_t stream)
{
    (void)in_sizes; (void)n_in; (void)out_size;

    const float* x    = (const float*)d_in[0];
    const float* wq   = (const float*)d_in[1];
    const float* wk   = (const float*)d_in[2];
    const float* wv   = (const float*)d_in[3];
    const float* wo   = (const float*)d_in[4];
    const float* w1   = (const float*)d_in[5];
    const float* b1   = (const float*)d_in[6];
    const float* w2   = (const float*)d_in[7];
    const float* b2   = (const float*)d_in[8];
    const float* ln1g = (const float*)d_in[9];
    const float* ln1b = (const float*)d_in[10];
    const float* ln2g = (const float*)d_in[11];
    const float* ln2b = (const float*)d_in[12];
    float* out = (float*)d_out;

    // ---- workspace layout (bytes), fixed part ~90.2 MB ----
    const size_t QKV_BYTES = (size_t)MROWS * QKVLD * 2;      // 50.33 MB
    const size_t Y_BYTES   = (size_t)MROWS * D_MODEL * 4;    // 33.55 MB
    unsigned char* base = (unsigned char*)d_ws;
    unsigned short* qkv  = (unsigned short*)(base);
    float*          y    = (float*)(base + QKV_BYTES);
    unsigned short* Wqkv = (unsigned short*)(base + QKV_BYTES + Y_BYTES);
    unsigned short* wo_t = Wqkv + 3 * 512 * 512;
    unsigned short* w1_t = wo_t + 512 * 512;
    unsigned short* w2_t = w1_t + 2048 * 512;
    unsigned short* hid  = w2_t + 2048 * 512;

    const size_t hid_off = (size_t)((unsigned char*)hid - base);
    const size_t avail = (ws_size > hid_off) ? (ws_size - hid_off) : 0;
    int chunk = (int)(avail / ((size_t)DFF * 2));
    chunk &= ~127;
    if (chunk > MROWS) chunk = MROWS;
    if (chunk < 128)   chunk = 128;

    float* y2 = (float*)qkv;                       // qkv dead after WO GEMM
    unsigned short* x1b = (unsigned short*)d_out;  // bf16 scratch inside d_out

    // ---- weight packing ----
    pack_qkv<<<1024, 256, 0, stream>>>(wq, wk, wv, Wqkv);
    pack_t<<<(512 * 512) / 256, 256, 0, stream>>>(wo, wo_t, 512, 512);
    pack_t<<<(2048 * 512) / 256, 256, 0, stream>>>(w1, w1_t, 512, 2048);
    pack_t<<<(2048 * 512) / 256, 256, 0, stream>>>(w2, w2_t, 2048, 512);

    const dim3 blk(256);

    // 1) fused q|k|v projection: x[M][512] @ Wqkv^T -> qkv[M][1536]
    mfma_gemm<true, false, false, false, false>
        <<<dim3(12, MROWS / 128), blk, 0, stream>>>(x, Wqkv, nullptr, nullptr,
                                                    qkv, 512, 512, QKVLD);

    // 2) flash attention (O bf16 in place over q section)
    mfma_attn<<<dim3(SEQ / 128, BATCH * NHEAD), dim3(512), 0, stream>>>(qkv);

    // 3) y = O @ wo + x   (fp32 out)
    mfma_gemm<false, false, false, true, true>
        <<<dim3(4, MROWS / 128), blk, 0, stream>>>(qkv, wo_t, nullptr, x, y,
                                                   512, QKVLD, 512);

    // 4) x1 = LN1(y): fp32 in place (residual for FFN2) + bf16 into d_out
    ln_kernel<true><<<MROWS / 4, blk, 0, stream>>>(y, ln1g, ln1b, y, x1b);

    // 5+6) FFN, chunked over rows (chunk multiple of 128)
    for (int r0 = 0; r0 < MROWS; r0 += chunk) {
        const int rows = (r0 + chunk <= MROWS) ? chunk : (MROWS - r0);
        mfma_gemm<false, true, true, false, false>
            <<<dim3(DFF / 128, rows / 128), blk, 0, stream>>>(
                x1b + (size_t)r0 * D_MODEL, w1_t, b1, nullptr, hid,
                512, 512, DFF);
        mfma_gemm<false, true, false, true, true>
            <<<dim3(4, rows / 128), blk, 0, stream>>>(
                hid, w2_t, b2, y + (size_t)r0 * D_MODEL,
                y2 + (size_t)r0 * D_MODEL, DFF, DFF, 512);
    }

    // 7) out = LN2(y2)
    ln_kernel<false><<<MROWS / 4, blk, 0, stream>>>(y2, ln2g, ln2b, out, nullptr);
}

// Round 5
// 350.344 us; speedup vs baseline: 9.3128x; 1.5216x over previous
//
#include <hip/hip_runtime.h>
#include <hip/hip_bf16.h>
#include <math.h>

// ---------------------------------------------------------------------------
// EncoderLayer, bf16-MFMA mixed precision for MI355X (gfx950).
// B=8, S=2048, D=512, H=8, DK=64, DFF=2048, M=16384.
// All GEMMs + attention matmuls: mfma_f32_16x16x32_bf16 (fp32 accumulate).
// Softmax (exp2 domain), LayerNorm, residuals, bias: fp32.
// Round-5 changes: Ps stride 72->76 (kills 4-way ds_write conflicts);
// defer-max softmax (skip max-reduce+rescale unless pmax > m+8) + lazy
// end-of-loop sum reduction (removes 8 shuffles/row/tile from common path);
// s_setprio around attn MFMA clusters; x pre-cast to bf16 (QKV GEMM loop
// loses 64 VALU cast ops per thread per K-step).
// ---------------------------------------------------------------------------

#define D_MODEL 512
#define NHEAD   8
#define DKH     64
#define SEQ     2048
#define BATCH   8
#define DFF     2048
#define MROWS   (BATCH * SEQ)          // 16384
#define QKVLD   1536                   // fused q|k|v row stride

typedef __bf16 bf16x8 __attribute__((ext_vector_type(8)));
typedef float  f32x4  __attribute__((ext_vector_type(4)));

__device__ __forceinline__ unsigned short f2bf(float f) {
    union { float f; unsigned u; } v; v.f = f;
    return (unsigned short)((v.u + 0x7FFFu + ((v.u >> 16) & 1u)) >> 16);
}

__device__ __forceinline__ float fexp2(float x) {   // raw v_exp_f32 (2^x)
    float r; asm("v_exp_f32 %0, %1" : "=v"(r) : "v"(x)); return r;
}

__device__ __forceinline__ f32x4 mfma16(bf16x8 a, bf16x8 b, f32x4 c) {
    return __builtin_amdgcn_mfma_f32_16x16x32_bf16(a, b, c, 0, 0, 0);
}

// ---------------------------------------------------------------------------
// bf16 MFMA GEMM: C[M,N] = A[M,K] * Bt[N,K]^T  (+bias, +relu, +fp32 residual)
// 128x128 tile, BK=32, 256 threads = 4 waves, each wave a 64x64 quadrant
// (4x4 fragments of 16x16x32). LDS stride 40. Register prefetch of kt+1.
// ---------------------------------------------------------------------------
template<bool BIAS, bool RELU, bool RES, bool OUTF32>
__global__ __launch_bounds__(256)
void mfma_gemm(const unsigned short* __restrict__ Av,
               const unsigned short* __restrict__ Bt,
               const float* __restrict__ bias, const float* __restrict__ res,
               void* __restrict__ Cv, int Kdim, int lda, int ldc)
{
    __shared__ unsigned short As[128][40];
    __shared__ unsigned short Bs[128][40];

    const int tid  = threadIdx.x;
    const int lane = tid & 63;
    const int w    = tid >> 6;
    const int mq   = (w >> 1) << 6;    // wave quadrant row
    const int nq   = (w & 1) << 6;     // wave quadrant col
    const int lrow = lane & 15;
    const int g    = lane >> 4;
    const int lk   = g << 3;           // k offset of this lane's 8 elems

    const int row0 = blockIdx.y << 7;
    const int col0 = blockIdx.x << 7;

    const int sr = tid >> 1;           // staging row 0..127
    const int sk = (tid & 1) << 4;     // staging k offset 0/16

    uint4 sA0, sA1, sB0, sB1;
    auto loadA = [&](int kt) {
        const unsigned short* ap = Av + (size_t)(row0 + sr) * lda + kt + sk;
        sA0 = *(const uint4*)ap;
        sA1 = *(const uint4*)(ap + 8);
    };
    auto loadB = [&](int kt) {
        const unsigned short* bp = Bt + (size_t)(col0 + sr) * Kdim + kt + sk;
        sB0 = *(const uint4*)bp;
        sB1 = *(const uint4*)(bp + 8);
    };

    const f32x4 zero = {0.f, 0.f, 0.f, 0.f};
    f32x4 acc[4][4];
    #pragma unroll
    for (int i = 0; i < 4; ++i)
        #pragma unroll
        for (int j = 0; j < 4; ++j) acc[i][j] = zero;

    loadA(0); loadB(0);

    for (int kt = 0; kt < Kdim; kt += 32) {
        __syncthreads();   // previous iteration's frag reads complete
        *(uint4*)&As[sr][sk]     = sA0;
        *(uint4*)&As[sr][sk + 8] = sA1;
        *(uint4*)&Bs[sr][sk]     = sB0;
        *(uint4*)&Bs[sr][sk + 8] = sB1;
        __syncthreads();

        if (kt + 32 < Kdim) { loadA(kt + 32); loadB(kt + 32); }  // in flight

        bf16x8 af[4], bfv[4];
        #pragma unroll
        for (int mf = 0; mf < 4; ++mf)
            af[mf] = *(const bf16x8*)&As[mq + mf * 16 + lrow][lk];
        #pragma unroll
        for (int nf = 0; nf < 4; ++nf)
            bfv[nf] = *(const bf16x8*)&Bs[nq + nf * 16 + lrow][lk];
        #pragma unroll
        for (int mf = 0; mf < 4; ++mf)
            #pragma unroll
            for (int nf = 0; nf < 4; ++nf)
                acc[mf][nf] = mfma16(af[mf], bfv[nf], acc[mf][nf]);
    }

    // epilogue: C/D layout col = lane&15, row = 4*(lane>>4)+reg
    const int orow = row0 + mq + g * 4;
    const int ocol = col0 + nq + lrow;
    #pragma unroll
    for (int mf = 0; mf < 4; ++mf) {
        #pragma unroll
        for (int nf = 0; nf < 4; ++nf) {
            const int cc = ocol + nf * 16;
            float bv = 0.f;
            if constexpr (BIAS) bv = bias[cc];
            #pragma unroll
            for (int r = 0; r < 4; ++r) {
                const int rr = orow + mf * 16 + r;
                float v = acc[mf][nf][r];
                if constexpr (BIAS) v += bv;
                if constexpr (RELU) v = fmaxf(v, 0.f);
                if constexpr (RES)  v += res[(size_t)rr * ldc + cc];
                if constexpr (OUTF32) ((float*)Cv)[(size_t)rr * ldc + cc] = v;
                else ((unsigned short*)Cv)[(size_t)rr * ldc + cc] = f2bf(v);
            }
        }
    }
}

// ---------------------------------------------------------------------------
// bf16 MFMA flash attention. Block = 8 waves, 128 Q-rows (16 per wave),
// KV tiles of 64, K/V register prefetch. Softmax in exp2 domain (Q weights
// carry 1/sqrt(dk)*log2e). Defer-max: rescale only when a row's tile max
// exceeds the running max by >8; row-sum reduced once at the end.
// qkv layout [M][1536], q|k|v at cols 0/512/1024, head col h*64.
// ---------------------------------------------------------------------------
__global__ __launch_bounds__(512)
void mfma_attn(unsigned short* __restrict__ qkv)
{
    __shared__ unsigned short Ks[64][72];    // K tile [kv][dk]
    __shared__ unsigned short Vt[64][72];    // V transposed [dk][kv]
    __shared__ unsigned short Ps[128][76];   // P [qrow][kv]; stride 76:
                                             // conflict-free b16 stores

    const int tid  = threadIdx.x;
    const int lane = tid & 63;
    const int w    = tid >> 6;
    const int lrow = lane & 15;
    const int g    = lane >> 4;
    const int lk   = g << 3;

    const int bh = blockIdx.y;
    const int b  = bh >> 3, h = bh & 7;
    const int s0 = blockIdx.x << 7;

    unsigned short* qptr = qkv + ((size_t)(b * SEQ + s0)) * QKVLD + h * DKH;
    const unsigned short* kbase = qkv + ((size_t)(b * SEQ)) * QKVLD + 512 + h * DKH;
    const unsigned short* vbase = qkv + ((size_t)(b * SEQ)) * QKVLD + 1024 + h * DKH;

    // Q fragments (rows w*16+lrow), pre-scaled by 0.125*log2e via weight pack
    bf16x8 qf[2];
    {
        const unsigned short* qp = qptr + (size_t)(w * 16 + lrow) * QKVLD;
        qf[0] = *(const bf16x8*)(qp + lk);
        qf[1] = *(const bf16x8*)(qp + 32 + lk);
    }

    // staging indices
    const int kr = tid >> 3, kc = (tid & 7) << 3;   // K: 64 rows x 64 cols
    const int vr = lane,     vc = w << 3;           // V: row=lane, 8-col slab

    uint4 kreg, vreg;
    auto loadKV = [&](int t0) {
        kreg = *(const uint4*)(kbase + (size_t)(t0 + kr) * QKVLD + kc);
        vreg = *(const uint4*)(vbase + (size_t)(t0 + vr) * QKVLD + vc);
    };
    loadKV(0);

    const f32x4 zero = {0.f, 0.f, 0.f, 0.f};
    f32x4 oacc[4];                    // [dk frag]; elem r -> q-row w*16+4g+r
    float mrun[4], lpart[4];          // running max, per-lane partial sum
    #pragma unroll
    for (int i = 0; i < 4; ++i) { oacc[i] = zero; mrun[i] = -INFINITY; lpart[i] = 0.f; }

    for (int t0 = 0; t0 < SEQ; t0 += 64) {
        __syncthreads();   // previous tile's LDS reads complete
        *(uint4*)&Ks[kr][kc] = kreg;
        {
            const unsigned short* vu = (const unsigned short*)&vreg;
            #pragma unroll
            for (int j = 0; j < 8; ++j) Vt[vc + j][vr] = vu[j];
        }
        __syncthreads();

        if (t0 + 64 < SEQ) loadKV(t0 + 64);   // prefetch, in flight over compute

        // S = Q K^T : per wave 16x64; acc elem r -> q-row 4g+r, col nf*16+lrow
        f32x4 sacc[4];
        #pragma unroll
        for (int nf = 0; nf < 4; ++nf) sacc[nf] = zero;
        __builtin_amdgcn_s_setprio(1);
        #pragma unroll
        for (int kk = 0; kk < 2; ++kk) {
            #pragma unroll
            for (int nf = 0; nf < 4; ++nf) {
                const bf16x8 kf = *(const bf16x8*)&Ks[nf * 16 + lrow][kk * 32 + lk];
                sacc[nf] = mfma16(qf[kk], kf, sacc[nf]);
            }
        }
        __builtin_amdgcn_s_setprio(0);

        // ---- defer-max online softmax (exp2 domain) ----
        float pmax[4];
        bool need = false;
        #pragma unroll
        for (int r = 0; r < 4; ++r) {
            pmax[r] = fmaxf(fmaxf(sacc[0][r], sacc[1][r]),
                            fmaxf(sacc[2][r], sacc[3][r]));
            need |= (pmax[r] > mrun[r] + 8.f);
        }
        if (__any(need)) {   // rare after first tile: full max-reduce + rescale
            #pragma unroll
            for (int r = 0; r < 4; ++r) {
                float mt = pmax[r];
                mt = fmaxf(mt, __shfl_xor(mt, 1, 16));
                mt = fmaxf(mt, __shfl_xor(mt, 2, 16));
                mt = fmaxf(mt, __shfl_xor(mt, 4, 16));
                mt = fmaxf(mt, __shfl_xor(mt, 8, 16));
                const float mnew = fmaxf(mrun[r], mt);
                const float alpha = fexp2(mrun[r] - mnew);  // first tile: 0
                mrun[r] = mnew;
                lpart[r] *= alpha;
                #pragma unroll
                for (int nf = 0; nf < 4; ++nf) oacc[nf][r] *= alpha;
            }
        }
        // common path: exp2 with frozen max (bounded by 2^8), lazy sum
        #pragma unroll
        for (int r = 0; r < 4; ++r) {
            #pragma unroll
            for (int nf = 0; nf < 4; ++nf) {
                const float p = fexp2(sacc[nf][r] - mrun[r]);
                lpart[r] += p;
                Ps[w * 16 + g * 4 + r][nf * 16 + lrow] = f2bf(p);
            }
        }

        // O += P V
        __builtin_amdgcn_s_setprio(1);
        #pragma unroll
        for (int kk = 0; kk < 2; ++kk) {
            const bf16x8 pf = *(const bf16x8*)&Ps[w * 16 + lrow][kk * 32 + lk];
            #pragma unroll
            for (int nf = 0; nf < 4; ++nf) {
                const bf16x8 vf = *(const bf16x8*)&Vt[nf * 16 + lrow][kk * 32 + lk];
                oacc[nf] = mfma16(pf, vf, oacc[nf]);
            }
        }
        __builtin_amdgcn_s_setprio(0);
    }

    // final row-sum reduction (once), normalize, write O bf16 in place
    #pragma unroll
    for (int r = 0; r < 4; ++r) {
        float l = lpart[r];
        l += __shfl_xor(l, 1, 16);
        l += __shfl_xor(l, 2, 16);
        l += __shfl_xor(l, 4, 16);
        l += __shfl_xor(l, 8, 16);
        const float inv = 1.f / l;
        #pragma unroll
        for (int nf = 0; nf < 4; ++nf)
            qptr[(size_t)(w * 16 + g * 4 + r) * QKVLD + nf * 16 + lrow] =
                f2bf(oacc[nf][r] * inv);
    }
}

// ---------------------------------------------------------------------------
// LayerNorm rows of 512; one wave per row. Optional bf16 secondary output.
// Safe in-place (outf == in): each wave reads its row fully before writing.
// ---------------------------------------------------------------------------
template<bool WB>
__global__ __launch_bounds__(256)
void ln_kernel(const float* __restrict__ in, const float* __restrict__ gg,
               const float* __restrict__ bb, float* __restrict__ outf,
               unsigned short* __restrict__ outb)
{
    const int row = blockIdx.x * 4 + (threadIdx.x >> 6);
    const int lane = threadIdx.x & 63;
    const float* p = in + (size_t)row * D_MODEL;

    const float4 a = *(const float4*)(p + lane * 4);
    const float4 c = *(const float4*)(p + 256 + lane * 4);
    float sum = a.x + a.y + a.z + a.w + c.x + c.y + c.z + c.w;
    float sq  = a.x*a.x + a.y*a.y + a.z*a.z + a.w*a.w
              + c.x*c.x + c.y*c.y + c.z*c.z + c.w*c.w;
    #pragma unroll
    for (int msk = 1; msk < 64; msk <<= 1) {
        sum += __shfl_xor(sum, msk, 64);
        sq  += __shfl_xor(sq,  msk, 64);
    }
    const float mean = sum * (1.f / 512.f);
    const float var  = sq * (1.f / 512.f) - mean * mean;
    const float rs   = rsqrtf(var + 1e-5f);

    const float4 g0 = *(const float4*)(gg + lane * 4);
    const float4 g1 = *(const float4*)(gg + 256 + lane * 4);
    const float4 b0 = *(const float4*)(bb + lane * 4);
    const float4 b1 = *(const float4*)(bb + 256 + lane * 4);

    float4 o0, o1;
    o0.x = (a.x - mean) * rs * g0.x + b0.x;
    o0.y = (a.y - mean) * rs * g0.y + b0.y;
    o0.z = (a.z - mean) * rs * g0.z + b0.z;
    o0.w = (a.w - mean) * rs * g0.w + b0.w;
    o1.x = (c.x - mean) * rs * g1.x + b1.x;
    o1.y = (c.y - mean) * rs * g1.y + b1.y;
    o1.z = (c.z - mean) * rs * g1.z + b1.z;
    o1.w = (c.w - mean) * rs * g1.w + b1.w;
    *(float4*)(outf + (size_t)row * D_MODEL + lane * 4) = o0;
    *(float4*)(outf + (size_t)row * D_MODEL + 256 + lane * 4) = o1;
    if constexpr (WB) {
        uint2 pa, pb;
        pa.x = f2bf(o0.x) | ((unsigned)f2bf(o0.y) << 16);
        pa.y = f2bf(o0.z) | ((unsigned)f2bf(o0.w) << 16);
        pb.x = f2bf(o1.x) | ((unsigned)f2bf(o1.y) << 16);
        pb.y = f2bf(o1.z) | ((unsigned)f2bf(o1.w) << 16);
        *(uint2*)(outb + (size_t)row * D_MODEL + lane * 4) = pa;
        *(uint2*)(outb + (size_t)row * D_MODEL + 256 + lane * 4) = pb;
    }
}

// ---------------------------------------------------------------------------
// fp32 -> bf16 cast, 8 elems/thread
// ---------------------------------------------------------------------------
__global__ __launch_bounds__(256)
void cast_bf16(const float* __restrict__ in, unsigned short* __restrict__ out)
{
    const size_t i = ((size_t)blockIdx.x * 256 + threadIdx.x) * 8;
    const float4 a = *(const float4*)(in + i);
    const float4 b = *(const float4*)(in + i + 4);
    uint4 o;
    o.x = f2bf(a.x) | ((unsigned)f2bf(a.y) << 16);
    o.y = f2bf(a.z) | ((unsigned)f2bf(a.w) << 16);
    o.z = f2bf(b.x) | ((unsigned)f2bf(b.y) << 16);
    o.w = f2bf(b.z) | ((unsigned)f2bf(b.w) << 16);
    *(uint4*)(out + i) = o;
}

// ---------------------------------------------------------------------------
// Weight packing: per-head q/k/v weights -> rows 0..511 / 512..1023 /
// 1024..1535 of Wqkv[1536][512] bf16. q scaled by 0.125*log2e (exp2 softmax).
// ---------------------------------------------------------------------------
__global__ __launch_bounds__(256)
void pack_qkv(const float* __restrict__ wq, const float* __restrict__ wk,
              const float* __restrict__ wv, unsigned short* __restrict__ Wqkv)
{
    const int idx = blockIdx.x * 256 + threadIdx.x;   // n*512 + d, n in 0..511
    const int n = idx >> 9, d = idx & 511;
    const int h = n >> 6, c = n & 63;
    const size_t src = ((size_t)h * 512 + d) * 64 + c;
    Wqkv[idx]                 = f2bf(wq[src] * 0.18033688f);  // 0.125 * log2(e)
    Wqkv[idx + 512 * 512]     = f2bf(wk[src]);
    Wqkv[idx + 2 * 512 * 512] = f2bf(wv[src]);
}

// transpose-cast: in fp32 [K][N] -> out bf16 [N][K]
__global__ __launch_bounds__(256)
void pack_t(const float* __restrict__ in, unsigned short* __restrict__ out,
            int K, int N)
{
    const int idx = blockIdx.x * 256 + threadIdx.x;
    const int n = idx / K, k = idx % K;
    out[idx] = f2bf(in[(size_t)k * N + n]);
}

// ---------------------------------------------------------------------------
extern "C" void kernel_launch(void* const* d_in, const int* in_sizes, int n_in,
                              void* d_out, int out_size, void* d_ws, size_t ws_size,
                              hipStream_t stream)
{
    (void)in_sizes; (void)n_in; (void)out_size;

    const float* x    = (const float*)d_in[0];
    const float* wq   = (const float*)d_in[1];
    const float* wk   = (const float*)d_in[2];
    const float* wv   = (const float*)d_in[3];
    const float* wo   = (const float*)d_in[4];
    const float* w1   = (const float*)d_in[5];
    const float* b1   = (const float*)d_in[6];
    const float* w2   = (const float*)d_in[7];
    const float* b2   = (const float*)d_in[8];
    const float* ln1g = (const float*)d_in[9];
    const float* ln1b = (const float*)d_in[10];
    const float* ln2g = (const float*)d_in[11];
    const float* ln2b = (const float*)d_in[12];
    float* out = (float*)d_out;

    // ---- workspace layout (bytes), fixed part ~90.2 MB ----
    const size_t QKV_BYTES = (size_t)MROWS * QKVLD * 2;      // 50.33 MB
    const size_t Y_BYTES   = (size_t)MROWS * D_MODEL * 4;    // 33.55 MB
    unsigned char* base = (unsigned char*)d_ws;
    unsigned short* qkv  = (unsigned short*)(base);
    float*          y    = (float*)(base + QKV_BYTES);
    unsigned short* Wqkv = (unsigned short*)(base + QKV_BYTES + Y_BYTES);
    unsigned short* wo_t = Wqkv + 3 * 512 * 512;
    unsigned short* w1_t = wo_t + 512 * 512;
    unsigned short* w2_t = w1_t + 2048 * 512;
    unsigned short* hid  = w2_t + 2048 * 512;

    const size_t hid_off = (size_t)((unsigned char*)hid - base);
    const size_t avail = (ws_size > hid_off) ? (ws_size - hid_off) : 0;
    int chunk = (int)(avail / ((size_t)DFF * 2));
    chunk &= ~127;
    if (chunk > MROWS) chunk = MROWS;
    if (chunk < 128)   chunk = 128;

    float* y2 = (float*)qkv;                       // qkv dead after WO GEMM
    // d_out doubles as scratch: xb (bf16 x) until LN1, then x1b (bf16 x1).
    unsigned short* xb  = (unsigned short*)d_out;
    unsigned short* x1b = (unsigned short*)d_out;

    // ---- weight packing + x cast ----
    pack_qkv<<<1024, 256, 0, stream>>>(wq, wk, wv, Wqkv);
    pack_t<<<(512 * 512) / 256, 256, 0, stream>>>(wo, wo_t, 512, 512);
    pack_t<<<(2048 * 512) / 256, 256, 0, stream>>>(w1, w1_t, 512, 2048);
    pack_t<<<(2048 * 512) / 256, 256, 0, stream>>>(w2, w2_t, 2048, 512);
    cast_bf16<<<(MROWS * D_MODEL) / (256 * 8), 256, 0, stream>>>(x, xb);

    const dim3 blk(256);

    // 1) fused q|k|v projection: xb[M][512] @ Wqkv^T -> qkv[M][1536]
    mfma_gemm<false, false, false, false>
        <<<dim3(12, MROWS / 128), blk, 0, stream>>>(xb, Wqkv, nullptr, nullptr,
                                                    qkv, 512, 512, QKVLD);

    // 2) flash attention (O bf16 in place over q section)
    mfma_attn<<<dim3(SEQ / 128, BATCH * NHEAD), dim3(512), 0, stream>>>(qkv);

    // 3) y = O @ wo + x   (fp32 out)
    mfma_gemm<false, false, true, true>
        <<<dim3(4, MROWS / 128), blk, 0, stream>>>(qkv, wo_t, nullptr, x, y,
                                                   512, QKVLD, 512);

    // 4) x1 = LN1(y): fp32 in place (residual for FFN2) + bf16 into d_out
    ln_kernel<true><<<MROWS / 4, blk, 0, stream>>>(y, ln1g, ln1b, y, x1b);

    // 5+6) FFN, chunked over rows (chunk multiple of 128)
    for (int r0 = 0; r0 < MROWS; r0 += chunk) {
        const int rows = (r0 + chunk <= MROWS) ? chunk : (MROWS - r0);
        mfma_gemm<true, true, false, false>
            <<<dim3(DFF / 128, rows / 128), blk, 0, stream>>>(
                x1b + (size_t)r0 * D_MODEL, w1_t, b1, nullptr, hid,
                512, 512, DFF);
        mfma_gemm<true, false, true, true>
            <<<dim3(4, rows / 128), blk, 0, stream>>>(
                hid, w2_t, b2, y + (size_t)r0 * D_MODEL,
                y2 + (size_t)r0 * D_MODEL, DFF, DFF, 512);
    }

    // 7) out = LN2(y2)
    ln_kernel<false><<<MROWS / 4, blk, 0, stream>>>(y2, ln2g, ln2b, out, nullptr);
}